// Round 4
// baseline (39.921 us; speedup 1.0000x reference)
//
#include <hip/hip_runtime.h>

#define TT 512
#define BB 32
#define CC 8000
#define NEGF (-1e30f)
#define LOG2E 1.4426950408889634f
#define LN2   0.6931471805599453f

#if __has_builtin(__builtin_amdgcn_exp2f)
#define EXP2F(x) __builtin_amdgcn_exp2f(x)
#else
#define EXP2F(x) exp2f(x)
#endif
#if __has_builtin(__builtin_amdgcn_logf)
#define LOG2F(x) __builtin_amdgcn_logf(x)   // v_log_f32 = log2
#else
#define LOG2F(x) log2f(x)
#endif

// ws layout: [0 .. 65*512) floats = chunk matrices (chunk 64 is a never-read
// pad for branch-free prefetch); counter uint at byte offset 65*512*4.
#define WS_MAT_FLOATS (65 * 512)
#define WS_CNT_OFF    (WS_MAT_FLOATS * 4)

__device__ __forceinline__ float lse2_2(float x, float y) {
    float m = fmaxf(x, y);
    return m + LOG2F(EXP2F(x - m) + EXP2F(y - m));
}
__device__ __forceinline__ float lse3_2(float x, float y, float z) {
    float m = fmaxf(fmaxf(x, y), z);
    return m + LOG2F(EXP2F(x - m) + EXP2F(y - m) + EXP2F(z - m));
}
__device__ __forceinline__ float lse4_2(float x, float y, float z, float w) {
    float m = fmaxf(fmaxf(x, y), fmaxf(z, w));
    return m + LOG2F(EXP2F(x - m) + EXP2F(y - m) + EXP2F(z - m) + EXP2F(w - m));
}
__device__ __forceinline__ float lse5_2(float x, float y, float z, float w, float v) {
    float m = fmaxf(fmaxf(fmaxf(x, y), fmaxf(z, w)), v);
    return m + LOG2F(EXP2F(x - m) + EXP2F(y - m) + EXP2F(z - m) + EXP2F(w - m) + EXP2F(v - m));
}

#define LOADM(dst, base)                                                       \
    dst##00 = (base)[ 0 * 32]; dst##01 = (base)[ 1 * 32];                      \
    dst##02 = (base)[ 2 * 32]; dst##03 = (base)[ 3 * 32];                      \
    dst##04 = (base)[ 4 * 32]; dst##11 = (base)[ 5 * 32];                      \
    dst##12 = (base)[ 6 * 32]; dst##13 = (base)[ 7 * 32];                      \
    dst##14 = (base)[ 8 * 32]; dst##22 = (base)[ 9 * 32];                      \
    dst##23 = (base)[10 * 32]; dst##24 = (base)[11 * 32];                      \
    dst##33 = (base)[12 * 32]; dst##34 = (base)[13 * 32];                      \
    dst##44 = (base)[14 * 32]

// Fused: 32 blocks x 64 threads. Phase A: thread (c,b) builds the chunk's
// upper-triangular 5x5 log2-semiring matrix product. The LAST block to finish
// (device-scope arrival counter) then runs the serial 64-chunk scan (phase B)
// in its single wave and writes the mean loss.
__global__ void ctc_fused(const float* __restrict__ logit,
                          const int* __restrict__ targets,
                          float* __restrict__ ws,
                          unsigned int* __restrict__ cnt,
                          float* __restrict__ out) {
    int tid = threadIdx.x;
    int gid = blockIdx.x * 64 + tid;           // 0..2047
    int b = gid & 31;
    int c = gid >> 5;                          // 0..63
    int a1 = targets[2 * b];
    int a2 = targets[2 * b + 1];
    bool sk = (a1 != a2);
    float skipadd = sk ? 0.0f : NEGF;

    // ---------------- Phase A ----------------
    int tstart = 8 * c, nst = 8;
    if (c == 0) { tstart = 1; nst = 7; }

    float l0[8], la[8], lb[8];
    #pragma unroll
    for (int s = 0; s < 8; ++s) {
        const float* row = logit + (size_t)((tstart + s) * BB + b) * CC;
        l0[s] = row[0]  * LOG2E;
        la[s] = row[a1] * LOG2E;
        lb[s] = row[a2] * LOG2E;
    }

    // Init Acc = T_{tstart}. pred: 0<-{0}; 1<-{0,1}; 2<-{1,2}; 3<-{1(sk),2,3}; 4<-{3,4}
    float m00 = l0[0], m01 = la[0], m02 = NEGF, m03 = NEGF, m04 = NEGF;
    float m11 = la[0], m12 = l0[0], m13 = sk ? lb[0] : NEGF, m14 = NEGF;
    float m22 = l0[0], m23 = lb[0], m24 = NEGF;
    float m33 = lb[0], m34 = l0[0];
    float m44 = l0[0];

    #pragma unroll
    for (int s = 1; s < 8; ++s) {
        if (s >= nst) break;
        float p0 = l0[s], pa = la[s], pb = lb[s];
        float t00 = p0 + m00;
        float t01 = pa + lse2_2(m00, m01);
        float t02 = p0 + lse2_2(m01, m02);
        float t03 = pb + lse3_2(m01 + skipadd, m02, m03);
        float t04 = p0 + lse2_2(m03, m04);
        float t11 = pa + m11;
        float t12 = p0 + lse2_2(m11, m12);
        float t13 = pb + lse3_2(m11 + skipadd, m12, m13);
        float t14 = p0 + lse2_2(m13, m14);
        float t22 = p0 + m22;
        float t23 = pb + lse2_2(m22, m23);
        float t24 = p0 + lse2_2(m23, m24);
        float t33 = pb + m33;
        float t34 = p0 + lse2_2(m33, m34);
        float t44 = p0 + m44;
        m00 = t00; m01 = t01; m02 = t02; m03 = t03; m04 = t04;
        m11 = t11; m12 = t12; m13 = t13; m14 = t14;
        m22 = t22; m23 = t23; m24 = t24;
        m33 = t33; m34 = t34;
        m44 = t44;
    }

    {
        float* w = ws + c * 512 + b;
        w[ 0 * 32] = m00; w[ 1 * 32] = m01; w[ 2 * 32] = m02; w[ 3 * 32] = m03;
        w[ 4 * 32] = m04; w[ 5 * 32] = m11; w[ 6 * 32] = m12; w[ 7 * 32] = m13;
        w[ 8 * 32] = m14; w[ 9 * 32] = m22; w[10 * 32] = m23; w[11 * 32] = m24;
        w[12 * 32] = m33; w[13 * 32] = m34; w[14 * 32] = m44;
    }

    // ---------------- Publish + elect last block ----------------
    __threadfence();                 // release: ws writes reach coherence point
    __syncthreads();                 // all threads in block have fenced
    __shared__ unsigned int sh_old;
    if (tid == 0) sh_old = atomicAdd(cnt, 1u);   // device-scope RMW
    __syncthreads();
    if (sh_old != 31u) return;       // not last: done

    // ---------------- Phase B (last block only; one wave) ----------------
    __threadfence();                 // acquire: invalidate stale cached lines

    int bb = (tid < BB) ? tid : 0;
    int aa1 = targets[2 * bb];
    const float* row0 = logit + (size_t)bb * CC;
    float A0 = row0[0]   * LOG2E;
    float A1 = row0[aa1] * LOG2E;
    float A2 = NEGF, A3 = NEGF, A4 = NEGF;

    float n00, n01, n02, n03, n04, n11, n12, n13, n14, n22, n23, n24, n33, n34, n44;
    float q00, q01, q02, q03, q04, q11, q12, q13, q14, q22, q23, q24, q33, q34, q44;
    const float* p = ws + bb;
    LOADM(n, p);
    for (int cc = 0; cc < 64; ++cc) {
        q00 = n00; q01 = n01; q02 = n02; q03 = n03; q04 = n04;
        q11 = n11; q12 = n12; q13 = n13; q14 = n14;
        q22 = n22; q23 = n23; q24 = n24;
        q33 = n33; q34 = n34; q44 = n44;
        const float* q = ws + (cc + 1) * 512 + bb;  // chunk 64 = pad, never used
        LOADM(n, q);
        float B0 = A0 + q00;
        float B1 = lse2_2(A0 + q01, A1 + q11);
        float B2 = lse3_2(A0 + q02, A1 + q12, A2 + q22);
        float B3 = lse4_2(A0 + q03, A1 + q13, A2 + q23, A3 + q33);
        float B4 = lse5_2(A0 + q04, A1 + q14, A2 + q24, A3 + q34, A4 + q44);
        A0 = B0; A1 = B1; A2 = B2; A3 = B3; A4 = B4;
    }

    float loglik2 = lse2_2(A3, A4);
    float loss = (tid < BB) ? (-0.5f * LN2 * loglik2) : 0.0f;  // -loglik_e / L
    #pragma unroll
    for (int off = 32; off > 0; off >>= 1)
        loss += __shfl_down(loss, off, 64);
    if (tid == 0) out[0] = loss * (1.0f / BB);
}

extern "C" void kernel_launch(void* const* d_in, const int* in_sizes, int n_in,
                              void* d_out, int out_size, void* d_ws, size_t ws_size,
                              hipStream_t stream) {
    const float* logit   = (const float*)d_in[0];
    const int*   targets = (const int*)d_in[2];
    float*        ws  = (float*)d_ws;
    unsigned int* cnt = (unsigned int*)((char*)d_ws + WS_CNT_OFF);
    float*        out = (float*)d_out;

    // Arrival counter must be 0 at kernel start on EVERY call (validation call
    // sees arbitrary ws; first timed replay sees 0xAA poison).
    hipMemsetAsync(cnt, 0, sizeof(unsigned int), stream);
    hipLaunchKernelGGL(ctc_fused, dim3(32), dim3(64), 0, stream,
                       logit, targets, ws, cnt, out);
}

// Round 5
// 20.608 us; speedup vs baseline: 1.9372x; 1.9372x over previous
//
#include <hip/hip_runtime.h>

#define TT 512
#define BB 32
#define CC 8000
#define LOG2E 1.4426950408889634f
#define LN2   0.6931471805599453f

#if __has_builtin(__builtin_amdgcn_exp2f)
#define EXP2F(x) __builtin_amdgcn_exp2f(x)
#else
#define EXP2F(x) exp2f(x)
#endif
#if __has_builtin(__builtin_amdgcn_logf)
#define LOG2F(x) __builtin_amdgcn_logf(x)   // v_log_f32 = log2
#else
#define LOG2F(x) log2f(x)
#endif

// ws layout: chunk c occupies floats [c*512, c*512+512): entry e (0..14 = packed
// upper-tri linear matrix, 15 = chunk exponent E_c) at offset e*32 + b.
// Chunk 64 is a never-used pad read by the branch-free prefetch.
// Election counter (uint) lives at float index 65*512. NO initialization needed:
// 32 consecutive atomicAdd results cover all residues mod 32 exactly once, so
// exactly one block sees (old & 31) == 31 regardless of the counter's start.
#define WS_CNT_OFF (65 * 512 * 4)

#define LOADM16(dst, base)                                                     \
    dst##00 = (base)[ 0 * 32]; dst##01 = (base)[ 1 * 32];                      \
    dst##02 = (base)[ 2 * 32]; dst##03 = (base)[ 3 * 32];                      \
    dst##04 = (base)[ 4 * 32]; dst##11 = (base)[ 5 * 32];                      \
    dst##12 = (base)[ 6 * 32]; dst##13 = (base)[ 7 * 32];                      \
    dst##14 = (base)[ 8 * 32]; dst##22 = (base)[ 9 * 32];                      \
    dst##23 = (base)[10 * 32]; dst##24 = (base)[11 * 32];                      \
    dst##33 = (base)[12 * 32]; dst##34 = (base)[13 * 32];                      \
    dst##44 = (base)[14 * 32]; dst##EE = (base)[15 * 32]

// 32 blocks x 64 threads. Phase A: thread (c,b) builds chunk c's 5x5 linear
// (probability-domain) transition product with per-step pow2 normalization.
// Last-arriving block runs the 64-chunk serial scan (phase B) in one wave.
__global__ __launch_bounds__(64) void ctc_fused(
        const float* __restrict__ logit,
        const int* __restrict__ targets,
        float* __restrict__ ws,
        unsigned int* __restrict__ cnt,
        float* __restrict__ out) {
    int tid = threadIdx.x;
    int gid = blockIdx.x * 64 + tid;           // 0..2047
    int b = gid & 31;
    int c = gid >> 5;                          // 0..63
    int a1 = targets[2 * b];
    int a2 = targets[2 * b + 1];
    float skf = (a1 != a2) ? 1.0f : 0.0f;      // skip transition 1->3 allowed?

    // ---------------- Phase A ----------------
    int tstart = (c == 0) ? 1 : 8 * c;
    int nst    = (c == 0) ? 7 : 8;

    float l0[8], la[8], lb[8];
    #pragma unroll
    for (int s = 0; s < 8; ++s) {              // s=7 of chunk 0 reads t=8: in-bounds, unused
        const float* row = logit + (size_t)((tstart + s) * BB + b) * CC;
        l0[s] = row[0]  * LOG2E;
        la[s] = row[a1] * LOG2E;
        lb[s] = row[a2] * LOG2E;
    }

    // Init M = T_{tstart} (normalized). pred: 0<-{0}; 1<-{0,1}; 2<-{1,2};
    // 3<-{1(sk),2,3}; 4<-{3,4}. Emissions: states 0,2,4 blank; 1 -> a1; 3 -> a2.
    float m0s = fmaxf(fmaxf(l0[0], la[0]), lb[0]);
    float P0 = EXP2F(l0[0] - m0s), Pa = EXP2F(la[0] - m0s), Pb = EXP2F(lb[0] - m0s);
    float Ec = m0s;
    float M00 = P0, M01 = Pa, M02 = 0.f, M03 = 0.f, M04 = 0.f;
    float M11 = Pa, M12 = P0, M13 = skf * Pb, M14 = 0.f;
    float M22 = P0, M23 = Pb, M24 = 0.f;
    float M33 = Pb, M34 = P0;
    float M44 = P0;

    #pragma unroll
    for (int s = 1; s < 8; ++s) {
        if (s >= nst) break;                   // only chunk 0 stops at 7
        float ms = fmaxf(fmaxf(l0[s], la[s]), lb[s]);
        float q0 = EXP2F(l0[s] - ms);
        float qa = EXP2F(la[s] - ms);
        float qb = EXP2F(lb[s] - ms);
        Ec += ms;
        float n00 = M00 * q0;
        float n01 = (M00 + M01) * qa;
        float n02 = (M01 + M02) * q0;
        float n03 = fmaf(skf, M01, M02 + M03) * qb;
        float n04 = (M03 + M04) * q0;
        float n11 = M11 * qa;
        float n12 = (M11 + M12) * q0;
        float n13 = fmaf(skf, M11, M12 + M13) * qb;
        float n14 = (M13 + M14) * q0;
        float n22 = M22 * q0;
        float n23 = (M22 + M23) * qb;
        float n24 = (M23 + M24) * q0;
        float n33 = M33 * qb;
        float n34 = (M33 + M34) * q0;
        float n44 = M44 * q0;
        M00 = n00; M01 = n01; M02 = n02; M03 = n03; M04 = n04;
        M11 = n11; M12 = n12; M13 = n13; M14 = n14;
        M22 = n22; M23 = n23; M24 = n24;
        M33 = n33; M34 = n34;
        M44 = n44;
    }

    {
        float* w = ws + c * 512 + b;
        w[ 0 * 32] = M00; w[ 1 * 32] = M01; w[ 2 * 32] = M02; w[ 3 * 32] = M03;
        w[ 4 * 32] = M04; w[ 5 * 32] = M11; w[ 6 * 32] = M12; w[ 7 * 32] = M13;
        w[ 8 * 32] = M14; w[ 9 * 32] = M22; w[10 * 32] = M23; w[11 * 32] = M24;
        w[12 * 32] = M33; w[13 * 32] = M34; w[14 * 32] = M44; w[15 * 32] = Ec;
    }

    // ---------------- Publish + elect last block (no counter init needed) ----
    __threadfence();                 // release: ws writes to coherence point
    __syncthreads();
    __shared__ unsigned int sh_old;
    if (tid == 0) sh_old = atomicAdd(cnt, 1u);
    __syncthreads();
    if ((sh_old & 31u) != 31u) return;
    __threadfence();                 // acquire: drop stale cached ws lines

    // ---------------- Phase B (last block; one wave; zero transcendentals) ---
    int bb = (tid < BB) ? tid : 0;
    int t1 = targets[2 * bb];
    const float* row0 = logit + (size_t)bb * CC;
    float l00 = row0[0] * LOG2E, la0 = row0[t1] * LOG2E;
    float mi = fmaxf(l00, la0);
    float A0 = EXP2F(l00 - mi), A1 = EXP2F(la0 - mi);
    float A2 = 0.f, A3 = 0.f, A4 = 0.f;
    double Ed = (double)mi;          // exponent: double + exact int, no drift
    int    Ei = 0;

    float n00, n01, n02, n03, n04, n11, n12, n13, n14, n22, n23, n24, n33, n34, n44, nEE;
    float q00, q01, q02, q03, q04, q11, q12, q13, q14, q22, q23, q24, q33, q34, q44, qEE;
    const float* p = ws + bb;
    LOADM16(n, p);
    for (int cc = 0; cc < 64; ++cc) {
        q00 = n00; q01 = n01; q02 = n02; q03 = n03; q04 = n04;
        q11 = n11; q12 = n12; q13 = n13; q14 = n14;
        q22 = n22; q23 = n23; q24 = n24;
        q33 = n33; q34 = n34; q44 = n44; qEE = nEE;
        const float* np = ws + (cc + 1) * 512 + bb;   // chunk 64 = pad
        LOADM16(n, np);
        float B0 = A0 * q00;
        float B1 = fmaf(A0, q01, A1 * q11);
        float B2 = fmaf(A0, q02, fmaf(A1, q12, A2 * q22));
        float B3 = fmaf(A0, q03, fmaf(A1, q13, fmaf(A2, q23, A3 * q33)));
        float B4 = fmaf(A0, q04, fmaf(A1, q14, fmaf(A2, q24, fmaf(A3, q34, A4 * q44))));
        Ed += (double)qEE;
        float mx = fmaxf(fmaxf(fmaxf(B0, B1), fmaxf(B2, B3)), B4);
        int ex = (int)((__float_as_uint(mx) >> 23) & 0xffu) - 127;
        float sc = __uint_as_float((unsigned)(127 - ex) << 23);  // exact 2^-ex
        Ei += ex;
        A0 = B0 * sc; A1 = B1 * sc; A2 = B2 * sc; A3 = B3 * sc; A4 = B4 * sc;
    }

    float ll2 = (float)(Ed + (double)Ei) + LOG2F(A3 + A4);   // log2 likelihood
    float loss = (tid < BB) ? (-0.5f * LN2 * ll2) : 0.0f;    // -loglik_e / L
    #pragma unroll
    for (int off = 32; off > 0; off >>= 1)
        loss += __shfl_down(loss, off, 64);
    if (tid == 0) out[0] = loss * (1.0f / BB);
}

extern "C" void kernel_launch(void* const* d_in, const int* in_sizes, int n_in,
                              void* d_out, int out_size, void* d_ws, size_t ws_size,
                              hipStream_t stream) {
    const float* logit   = (const float*)d_in[0];
    const int*   targets = (const int*)d_in[2];
    float*        ws  = (float*)d_ws;
    unsigned int* cnt = (unsigned int*)((char*)d_ws + WS_CNT_OFF);
    float*        out = (float*)d_out;

    hipLaunchKernelGGL(ctc_fused, dim3(32), dim3(64), 0, stream,
                       logit, targets, ws, cnt, out);
}